// Round 1
// baseline (350.593 us; speedup 1.0000x reference)
//
#include <hip/hip_runtime.h>
#include <math.h>

typedef __attribute__((ext_vector_type(4))) float f32x4;
typedef __attribute__((ext_vector_type(8))) short short8;

#define DEV __device__ __forceinline__

DEV short f2bf(float f){
  union { float f; unsigned u; } v; v.f = f;
  unsigned r = v.u + 0x7fffu + ((v.u >> 16) & 1u);
  return (short)(r >> 16);
}

// ---------------- weight transpose + f32->bf16 ----------------
__global__ __launch_bounds__(256) void transpose_bf16_kernel(
    const float* __restrict__ W, short* __restrict__ Wt, int K, int N)
{
  __shared__ float tile[32][33];
  int nb = blockIdx.x * 32, kb = blockIdx.y * 32;
  int tx = threadIdx.x & 31, ty = threadIdx.x >> 5;   // ty 0..7
  #pragma unroll
  for (int i = ty; i < 32; i += 8)
    tile[i][tx] = W[(size_t)(kb + i) * N + nb + tx];
  __syncthreads();
  #pragma unroll
  for (int i = ty; i < 32; i += 8)
    Wt[(size_t)(nb + i) * K + kb + tx] = f2bf(tile[tx][i]);
}

// ---------------- layernorm (f32 in, bf16 out), one row / block ----------------
__global__ __launch_bounds__(256) void ln_kernel(
    const float* __restrict__ x, const float* __restrict__ g,
    const float* __restrict__ b, short* __restrict__ out)
{
  int row = blockIdx.x;
  int tid = threadIdx.x;
  const float* xr = x + (size_t)row * 512;
  float2 v = *(const float2*)(xr + tid * 2);
  float s = v.x + v.y;
  float sq = v.x * v.x + v.y * v.y;
  #pragma unroll
  for (int off = 1; off < 64; off <<= 1) {
    s  += __shfl_xor(s, off);
    sq += __shfl_xor(sq, off);
  }
  __shared__ float ss[4], sg[4];
  int wid = tid >> 6, lane = tid & 63;
  if (lane == 0) { ss[wid] = s; sg[wid] = sq; }
  __syncthreads();
  s  = ss[0] + ss[1] + ss[2] + ss[3];
  sq = sg[0] + sg[1] + sg[2] + sg[3];
  float mu  = s * (1.0f / 512.0f);
  float var = sq * (1.0f / 512.0f) - mu * mu;
  float rstd = rsqrtf(var + 1e-5f);
  float2 gg = *(const float2*)(g + tid * 2);
  float2 bb = *(const float2*)(b + tid * 2);
  float o0 = (v.x - mu) * rstd * gg.x + bb.x;
  float o1 = (v.y - mu) * rstd * gg.y + bb.y;
  unsigned pack = (unsigned)(unsigned short)f2bf(o0)
                | ((unsigned)(unsigned short)f2bf(o1) << 16);
  *(unsigned*)(out + (size_t)row * 512 + tid * 2) = pack;
}

// ---------------- GEMM: C[M,N] = A[M,K] * Bt[N,K]^T  (bf16 in, f32 acc) ----------------
// EPI: 0 = plain -> bf16 ; 1 = +bias +resid -> f32 ; 2 = +bias, GELU -> bf16
template<int EPI, typename OutT>
__global__ __launch_bounds__(256) void gemm_bt_kernel(
    const short* __restrict__ A, const short* __restrict__ Bt,
    OutT* __restrict__ C, const float* __restrict__ bias,
    const float* __restrict__ resid, int M, int N, int K)
{
  __shared__ __align__(16) short As[128 * 32];
  __shared__ __align__(16) short Bs[128 * 32];
  int tid = threadIdx.x;
  int lane = tid & 63, wid = tid >> 6;
  int l16 = lane & 15, lq = lane >> 4;
  int bm = blockIdx.y, bn = blockIdx.x;
  int wm = wid >> 1, wn = wid & 1;

  f32x4 acc[4][4] = {};

  for (int k0 = 0; k0 < K; k0 += 32) {
    #pragma unroll
    for (int i = 0; i < 2; ++i) {
      int ci = i * 256 + tid;
      int row = ci >> 2, c4 = ci & 3;
      const short* ga = A  + (size_t)(bm * 128 + row) * K + k0 + c4 * 8;
      const short* gb = Bt + (size_t)(bn * 128 + row) * K + k0 + c4 * 8;
      __builtin_amdgcn_global_load_lds(
          (const __attribute__((address_space(1))) void*)ga,
          (__attribute__((address_space(3))) void*)((char*)As + (i * 4 + wid) * 1024),
          16, 0, 0);
      __builtin_amdgcn_global_load_lds(
          (const __attribute__((address_space(1))) void*)gb,
          (__attribute__((address_space(3))) void*)((char*)Bs + (i * 4 + wid) * 1024),
          16, 0, 0);
    }
    __syncthreads();
    short8 af[4], bfr[4];
    #pragma unroll
    for (int m = 0; m < 4; ++m)
      af[m] = *(const short8*)(As + (wm * 64 + m * 16 + l16) * 32 + lq * 8);
    #pragma unroll
    for (int n = 0; n < 4; ++n)
      bfr[n] = *(const short8*)(Bs + (wn * 64 + n * 16 + l16) * 32 + lq * 8);
    #pragma unroll
    for (int m = 0; m < 4; ++m)
      #pragma unroll
      for (int n = 0; n < 4; ++n)
        acc[m][n] = __builtin_amdgcn_mfma_f32_16x16x32_bf16(af[m], bfr[n], acc[m][n], 0, 0, 0);
    __syncthreads();
  }

  #pragma unroll
  for (int m = 0; m < 4; ++m) {
    #pragma unroll
    for (int n = 0; n < 4; ++n) {
      int col = bn * 128 + wn * 64 + n * 16 + l16;
      float bv = (EPI == 0) ? 0.0f : bias[col];
      #pragma unroll
      for (int r = 0; r < 4; ++r) {
        int row = bm * 128 + wm * 64 + m * 16 + lq * 4 + r;
        float v = acc[m][n][r];
        if (EPI == 1 || EPI == 2) v += bv;
        if (EPI == 2) v = 0.5f * v * (1.0f + erff(v * 0.70710678f));
        if (EPI == 1) v += resid[(size_t)row * N + col];
        if constexpr (sizeof(OutT) == 2)
          ((short*)C)[(size_t)row * N + col] = f2bf(v);
        else
          ((float*)C)[(size_t)row * N + col] = v;
      }
    }
  }
}

// ---------------- fused flash attention with diagonal mask (LSA) ----------------
// qkv: bf16 [B*2048, 1536] rows = [q(8h x 64) | k | v]; out: bf16 [B*2048, 512]
__global__ __launch_bounds__(256) void attn_kernel(
    const short* __restrict__ qkv, const float* __restrict__ temp_ptr,
    short* __restrict__ out)
{
  __shared__ __align__(16) short Ks[32 * 64];    // swizzled row-major [32][64]
  __shared__ __align__(16) short Vt[64][40];     // V^T, padded
  __shared__ __align__(16) short Pl[4][16][40];  // per-wave P tile, padded
  int tid = threadIdx.x;
  int lane = tid & 63, wid = tid >> 6;
  int l16 = lane & 15, lq = lane >> 4;
  int qb = blockIdx.x, bh = blockIdx.y;
  int b = bh >> 3, h = bh & 7;
  const short* base = qkv + (size_t)b * 2048 * 1536 + h * 64;
  const short* kp = base + 512;
  const short* vp = base + 1024;
  float scale = __expf(temp_ptr[0]);

  int qrow = qb * 64 + wid * 16 + l16;
  short8 qf[2];
  qf[0] = *(const short8*)(base + (size_t)qrow * 1536 + lq * 8);
  qf[1] = *(const short8*)(base + (size_t)qrow * 1536 + 32 + lq * 8);

  f32x4 accO[4] = {};
  float mrow[4], lrow[4];
  int myq[4];
  #pragma unroll
  for (int r = 0; r < 4; ++r) {
    mrow[r] = -1e30f; lrow[r] = 0.0f;
    myq[r] = qb * 64 + wid * 16 + lq * 4 + r;
  }

  for (int k0 = 0; k0 < 2048; k0 += 32) {
    { // stage K tile, XOR-swizzled (row = 128 B)
      int row = tid >> 3, c8 = tid & 7;
      short8 kv = *(const short8*)(kp + (size_t)(k0 + row) * 1536 + c8 * 8);
      int ba = (row * 128 + c8 * 16) ^ ((row & 7) << 4);
      *(short8*)((char*)Ks + ba) = kv;
    }
    { // stage V transposed
      int key = tid & 31, c8 = tid >> 5;
      short8 vv = *(const short8*)(vp + (size_t)(k0 + key) * 1536 + c8 * 8);
      #pragma unroll
      for (int i = 0; i < 8; ++i) Vt[c8 * 8 + i][key] = vv[i];
    }
    __syncthreads();

    // S = Q K^T  (16 q-rows x 32 keys per wave)
    f32x4 accS[2] = {};
    #pragma unroll
    for (int kh = 0; kh < 2; ++kh) {
      #pragma unroll
      for (int c = 0; c < 2; ++c) {
        int key = kh * 16 + l16;
        int ba = (key * 128 + c * 64 + lq * 16) ^ ((key & 7) << 4);
        short8 kf = *(const short8*)((char*)Ks + ba);
        accS[kh] = __builtin_amdgcn_mfma_f32_16x16x32_bf16(qf[c], kf, accS[kh], 0, 0, 0);
      }
    }

    // online softmax (rows live in 16-lane groups)
    #pragma unroll
    for (int r = 0; r < 4; ++r) {
      float s0 = accS[0][r] * scale;
      float s1 = accS[1][r] * scale;
      if (k0 + l16 == myq[r])      s0 = -1e30f;   // LSA diagonal mask
      if (k0 + 16 + l16 == myq[r]) s1 = -1e30f;
      float tmax = fmaxf(s0, s1);
      #pragma unroll
      for (int off = 1; off < 16; off <<= 1) tmax = fmaxf(tmax, __shfl_xor(tmax, off));
      float mnew = fmaxf(mrow[r], tmax);
      float alpha = __expf(mrow[r] - mnew);
      float p0 = __expf(s0 - mnew);
      float p1 = __expf(s1 - mnew);
      float rsum = p0 + p1;
      #pragma unroll
      for (int off = 1; off < 16; off <<= 1) rsum += __shfl_xor(rsum, off);
      lrow[r] = lrow[r] * alpha + rsum;
      mrow[r] = mnew;
      #pragma unroll
      for (int d = 0; d < 4; ++d) accO[d][r] *= alpha;
      Pl[wid][lq * 4 + r][l16]      = f2bf(p0);
      Pl[wid][lq * 4 + r][16 + l16] = f2bf(p1);
    }

    // O += P V
    #pragma unroll
    for (int d = 0; d < 4; ++d) {
      short8 vf = *(const short8*)(&Vt[d * 16 + l16][lq * 8]);
      short8 pf = *(const short8*)(&Pl[wid][l16][lq * 8]);
      accO[d] = __builtin_amdgcn_mfma_f32_16x16x32_bf16(pf, vf, accO[d], 0, 0, 0);
    }
    __syncthreads();
  }

  #pragma unroll
  for (int d = 0; d < 4; ++d)
    #pragma unroll
    for (int r = 0; r < 4; ++r) {
      float v = accO[d][r] / lrow[r];
      out[(size_t)(b * 2048 + myq[r]) * 512 + h * 64 + d * 16 + l16] = f2bf(v);
    }
}

// ---------------- launcher ----------------
extern "C" void kernel_launch(void* const* d_in, const int* in_sizes, int n_in,
                              void* d_out, int out_size, void* d_ws, size_t ws_size,
                              hipStream_t stream)
{
  const float* x    = (const float*)d_in[0];
  const float* ln1g = (const float*)d_in[1];
  const float* ln1b = (const float*)d_in[2];
  const float* Wqkv = (const float*)d_in[3];
  const float* temp = (const float*)d_in[4];
  const float* Wo   = (const float*)d_in[5];
  const float* bo   = (const float*)d_in[6];
  const float* ln2g = (const float*)d_in[7];
  const float* ln2b = (const float*)d_in[8];
  const float* W1   = (const float*)d_in[9];
  const float* b1   = (const float*)d_in[10];
  const float* W2   = (const float*)d_in[11];
  const float* b2   = (const float*)d_in[12];
  float* out = (float*)d_out;

  char* ws = (char*)d_ws;
  short* wqkv_t = (short*)(ws);                    // [1536][512] bf16
  short* wo_t   = (short*)(ws + 1572864);          // [512][512]
  short* w1_t   = (short*)(ws + 2097152);          // [2048][512]
  short* w2_t   = (short*)(ws + 4194304);          // [512][2048]
  short* h      = (short*)(ws + 6291456);          // [8192][512] bf16 (LN out, reused)
  short* qkv    = (short*)(ws + 14680064);         // [8192][1536] bf16
  short* attn   = (short*)(ws + 39845888);         // [8192][512] bf16
  float* y      = (float*)(ws + 48234496);         // [8192][512] f32
  short* t      = (short*)(ws + 14680064);         // [8192][2048] bf16 (reuses qkv+attn)
  // ws high-water: 65,011,712 bytes

  const int M = 8192;

  transpose_bf16_kernel<<<dim3(1536 / 32, 512 / 32),  256, 0, stream>>>(Wqkv, wqkv_t, 512, 1536);
  transpose_bf16_kernel<<<dim3(512 / 32, 512 / 32),   256, 0, stream>>>(Wo,   wo_t,   512, 512);
  transpose_bf16_kernel<<<dim3(2048 / 32, 512 / 32),  256, 0, stream>>>(W1,   w1_t,   512, 2048);
  transpose_bf16_kernel<<<dim3(512 / 32, 2048 / 32),  256, 0, stream>>>(W2,   w2_t,   2048, 512);

  ln_kernel<<<M, 256, 0, stream>>>(x, ln1g, ln1b, h);

  gemm_bt_kernel<0, short><<<dim3(1536 / 128, M / 128), 256, 0, stream>>>(
      h, wqkv_t, qkv, nullptr, nullptr, M, 1536, 512);

  attn_kernel<<<dim3(32, 32), 256, 0, stream>>>(qkv, temp, attn);

  gemm_bt_kernel<1, float><<<dim3(512 / 128, M / 128), 256, 0, stream>>>(
      attn, wo_t, y, bo, x, M, 512, 512);

  ln_kernel<<<M, 256, 0, stream>>>(y, ln2g, ln2b, h);

  gemm_bt_kernel<2, short><<<dim3(2048 / 128, M / 128), 256, 0, stream>>>(
      h, w1_t, t, b1, nullptr, M, 2048, 512);

  gemm_bt_kernel<1, float><<<dim3(512 / 128, M / 128), 256, 0, stream>>>(
      t, w2_t, out, b2, y, M, 512, 2048);

  hipMemcpyAsync(out + (size_t)M * 512, x, (size_t)M * 512 * sizeof(float),
                 hipMemcpyDeviceToDevice, stream);
}

// Round 2
// 294.872 us; speedup vs baseline: 1.1890x; 1.1890x over previous
//
#include <hip/hip_runtime.h>
#include <math.h>

typedef __attribute__((ext_vector_type(4))) float f32x4;
typedef __attribute__((ext_vector_type(8))) short short8;

#define DEV __device__ __forceinline__

DEV short f2bf(float f){
  union { float f; unsigned u; } v; v.f = f;
  unsigned r = v.u + 0x7fffu + ((v.u >> 16) & 1u);
  return (short)(r >> 16);
}
DEV float bf2f(short s){
  union { unsigned u; float f; } v; v.u = ((unsigned)(unsigned short)s) << 16; return v.f;
}

// ---------------- weight transpose + f32->bf16 ----------------
__global__ __launch_bounds__(256) void transpose_bf16_kernel(
    const float* __restrict__ W, short* __restrict__ Wt, int K, int N)
{
  __shared__ float tile[32][33];
  int nb = blockIdx.x * 32, kb = blockIdx.y * 32;
  int tx = threadIdx.x & 31, ty = threadIdx.x >> 5;   // ty 0..7
  #pragma unroll
  for (int i = ty; i < 32; i += 8)
    tile[i][tx] = W[(size_t)(kb + i) * N + nb + tx];
  __syncthreads();
  #pragma unroll
  for (int i = ty; i < 32; i += 8)
    Wt[(size_t)(nb + i) * K + kb + tx] = f2bf(tile[tx][i]);
}

// ---------------- layernorm (f32 in, bf16 out), one row / block ----------------
__global__ __launch_bounds__(256) void ln_kernel(
    const float* __restrict__ x, const float* __restrict__ g,
    const float* __restrict__ b, short* __restrict__ out)
{
  int row = blockIdx.x;
  int tid = threadIdx.x;
  const float* xr = x + (size_t)row * 512;
  float2 v = *(const float2*)(xr + tid * 2);
  float s = v.x + v.y;
  float sq = v.x * v.x + v.y * v.y;
  #pragma unroll
  for (int off = 1; off < 64; off <<= 1) {
    s  += __shfl_xor(s, off);
    sq += __shfl_xor(sq, off);
  }
  __shared__ float ss[4], sg[4];
  int wid = tid >> 6, lane = tid & 63;
  if (lane == 0) { ss[wid] = s; sg[wid] = sq; }
  __syncthreads();
  s  = ss[0] + ss[1] + ss[2] + ss[3];
  sq = sg[0] + sg[1] + sg[2] + sg[3];
  float mu  = s * (1.0f / 512.0f);
  float var = sq * (1.0f / 512.0f) - mu * mu;
  float rstd = rsqrtf(var + 1e-5f);
  float2 gg = *(const float2*)(g + tid * 2);
  float2 bb = *(const float2*)(b + tid * 2);
  float o0 = (v.x - mu) * rstd * gg.x + bb.x;
  float o1 = (v.y - mu) * rstd * gg.y + bb.y;
  unsigned pack = (unsigned)(unsigned short)f2bf(o0)
                | ((unsigned)(unsigned short)f2bf(o1) << 16);
  *(unsigned*)(out + (size_t)row * 512 + tid * 2) = pack;
}

// ---------------- GEMM: C[M,N] = A[M,K] * Bt[N,K]^T  (bf16 in, f32 acc) ----------------
// EPI: 0 = plain -> bf16 ; 1 = +bias +resid -> f32 ; 2 = +bias, GELU -> bf16
// EPI: 3 = plain -> bf16, plus transposed copy of cols>=1024 into vt [bh][64][2048]
template<int EPI, typename OutT>
__global__ __launch_bounds__(256) void gemm_bt_kernel(
    const short* __restrict__ A, const short* __restrict__ Bt,
    OutT* __restrict__ C, const float* __restrict__ bias,
    const float* __restrict__ resid, short* __restrict__ vt,
    int M, int N, int K)
{
  __shared__ __align__(16) short As[128 * 32];
  __shared__ __align__(16) short Bs[128 * 32];
  int tid = threadIdx.x;
  int lane = tid & 63, wid = tid >> 6;
  int l16 = lane & 15, lq = lane >> 4;
  int bm = blockIdx.y, bn = blockIdx.x;
  int wm = wid >> 1, wn = wid & 1;

  f32x4 acc[4][4] = {};

  for (int k0 = 0; k0 < K; k0 += 32) {
    #pragma unroll
    for (int i = 0; i < 2; ++i) {
      int ci = i * 256 + tid;
      int row = ci >> 2, c4 = ci & 3;
      const short* ga = A  + (size_t)(bm * 128 + row) * K + k0 + c4 * 8;
      const short* gb = Bt + (size_t)(bn * 128 + row) * K + k0 + c4 * 8;
      __builtin_amdgcn_global_load_lds(
          (const __attribute__((address_space(1))) void*)ga,
          (__attribute__((address_space(3))) void*)((char*)As + (i * 4 + wid) * 1024),
          16, 0, 0);
      __builtin_amdgcn_global_load_lds(
          (const __attribute__((address_space(1))) void*)gb,
          (__attribute__((address_space(3))) void*)((char*)Bs + (i * 4 + wid) * 1024),
          16, 0, 0);
    }
    __syncthreads();
    short8 af[4], bfr[4];
    #pragma unroll
    for (int m = 0; m < 4; ++m)
      af[m] = *(const short8*)(As + (wm * 64 + m * 16 + l16) * 32 + lq * 8);
    #pragma unroll
    for (int n = 0; n < 4; ++n)
      bfr[n] = *(const short8*)(Bs + (wn * 64 + n * 16 + l16) * 32 + lq * 8);
    #pragma unroll
    for (int m = 0; m < 4; ++m)
      #pragma unroll
      for (int n = 0; n < 4; ++n)
        acc[m][n] = __builtin_amdgcn_mfma_f32_16x16x32_bf16(af[m], bfr[n], acc[m][n], 0, 0, 0);
    __syncthreads();
  }

  #pragma unroll
  for (int m = 0; m < 4; ++m) {
    #pragma unroll
    for (int n = 0; n < 4; ++n) {
      int col = bn * 128 + wn * 64 + n * 16 + l16;
      float bv = (EPI == 0 || EPI == 3) ? 0.0f : bias[col];
      #pragma unroll
      for (int r = 0; r < 4; ++r) {
        int row = bm * 128 + wm * 64 + m * 16 + lq * 4 + r;
        float v = acc[m][n][r];
        if (EPI == 1 || EPI == 2) v += bv;
        if (EPI == 2) v = 0.5f * v * (1.0f + erff(v * 0.70710678f));
        if (EPI == 1) v += resid[(size_t)row * N + col];
        if constexpr (sizeof(OutT) == 2) {
          short bw = f2bf(v);
          ((short*)C)[(size_t)row * N + col] = bw;
          if (EPI == 3 && col >= 1024) {   // V columns -> transposed [bh][d][n]
            int c2 = col - 1024;           // h*64 + d
            int bb2 = row >> 11, nn = row & 2047;
            vt[(((size_t)(bb2 * 8 + (c2 >> 6))) * 64 + (c2 & 63)) * 2048 + nn] = bw;
          }
        } else {
          ((float*)C)[(size_t)row * N + col] = v;
        }
      }
    }
  }
}

// ---------------- fused flash attention with diagonal mask (LSA) ----------------
// qkv: bf16 [B*2048, 1536] rows = [q | k | v]; vt: bf16 [32 bh][64 d][2048 n]
// out: bf16 [B*2048, 512]
// 4 waves x 32 q-rows = 128 q-rows/block; KVBLK=64, double-buffered,
// fragment-major LDS staging via global_load_lds (conflict-free ds_read_b128).
__global__ __launch_bounds__(256, 2) void attn_kernel(
    const short* __restrict__ qkv, const short* __restrict__ vt,
    const float* __restrict__ temp_ptr, short* __restrict__ out)
{
  __shared__ __align__(16) short Ks[2][4096];   // [buf][(ksub*2+c)*64 + lane] * 8 shorts
  __shared__ __align__(16) short Vs[2][4096];   // [buf][(dsub*2+kc)*64 + lane] * 8 shorts
  __shared__ __align__(16) short Pl[4][32][72]; // per-wave P tile, padded rows

  int tid = threadIdx.x;
  int lane = tid & 63, wid = tid >> 6;
  int l16 = lane & 15, lq = lane >> 4;
  int qb = blockIdx.x, bh = blockIdx.y;
  int b = bh >> 3, h = bh & 7;

  const short* qbase = qkv + (size_t)b * 2048 * 1536 + h * 64;
  const short* kbase = qbase + 512;
  const short* vbase = vt + (size_t)bh * 64 * 2048;

  float scale = __expf(temp_ptr[0]);
  int q0 = qb * 128 + wid * 32;

  // Q fragments, pre-scaled (scale ~= 2^-3, exact in bf16)
  short8 qfrag[2][2];
  #pragma unroll
  for (int qf = 0; qf < 2; ++qf) {
    int qrow = q0 + qf * 16 + l16;
    #pragma unroll
    for (int c = 0; c < 2; ++c) {
      short8 raw = *(const short8*)(qbase + (size_t)qrow * 1536 + c * 32 + lq * 8);
      short8 sc;
      #pragma unroll
      for (int j = 0; j < 8; ++j) sc[j] = f2bf(bf2f(raw[j]) * scale);
      qfrag[qf][c] = sc;
    }
  }

  f32x4 accO[2][4] = {};
  float mrow[2][4], lrow[2][4];
  #pragma unroll
  for (int qf = 0; qf < 2; ++qf)
    #pragma unroll
    for (int r = 0; r < 4; ++r) { mrow[qf][r] = -1e30f; lrow[qf][r] = 0.0f; }

  auto STAGE = [&](int bufi, int k0) {
    #pragma unroll
    for (int i = 0; i < 2; ++i) {
      int w16 = i * 256 + tid;            // 0..511 = lane-write index
      int sub = w16 >> 7;                 // ksub / dsub
      int cc  = (w16 >> 6) & 1;           // d-chunk (K) / k-chunk (V)
      int lq2 = (w16 >> 4) & 3;
      int l2  = w16 & 15;
      const short* srcK = kbase + (size_t)(k0 + sub * 16 + l2) * 1536 + cc * 32 + lq2 * 8;
      __builtin_amdgcn_global_load_lds(
          (const __attribute__((address_space(1))) void*)srcK,
          (__attribute__((address_space(3))) void*)((char*)&Ks[bufi][0] + (i * 4 + wid) * 1024),
          16, 0, 0);
      const short* srcV = vbase + (size_t)(sub * 16 + l2) * 2048 + k0 + cc * 32 + lq2 * 8;
      __builtin_amdgcn_global_load_lds(
          (const __attribute__((address_space(1))) void*)srcV,
          (__attribute__((address_space(3))) void*)((char*)&Vs[bufi][0] + (i * 4 + wid) * 1024),
          16, 0, 0);
    }
  };

  STAGE(0, 0);
  asm volatile("s_waitcnt vmcnt(0)");
  __syncthreads();

  for (int k0 = 0; k0 < 2048; k0 += 64) {
    int cur = (k0 >> 6) & 1;
    if (k0 + 64 < 2048) STAGE(cur ^ 1, k0 + 64);   // prefetch overlaps compute

    const short* kls = &Ks[cur][0];
    const short* vls = &Vs[cur][0];

    // ---- S = Q K^T : accS[qf][ksub], rows q = qf*16+lq*4+r, cols key = ksub*16+l16
    f32x4 accS[2][4] = {};
    #pragma unroll
    for (int ksub = 0; ksub < 4; ++ksub) {
      short8 kf0 = *(const short8*)(kls + (ksub * 2 + 0) * 512 + lane * 8);
      short8 kf1 = *(const short8*)(kls + (ksub * 2 + 1) * 512 + lane * 8);
      #pragma unroll
      for (int qf = 0; qf < 2; ++qf) {
        accS[qf][ksub] = __builtin_amdgcn_mfma_f32_16x16x32_bf16(qfrag[qf][0], kf0, accS[qf][ksub], 0, 0, 0);
        accS[qf][ksub] = __builtin_amdgcn_mfma_f32_16x16x32_bf16(qfrag[qf][1], kf1, accS[qf][ksub], 0, 0, 0);
      }
    }

    // ---- online softmax
    #pragma unroll
    for (int qf = 0; qf < 2; ++qf) {
      #pragma unroll
      for (int r = 0; r < 4; ++r) {
        int qg = q0 + qf * 16 + lq * 4 + r;
        float s0 = accS[qf][0][r], s1 = accS[qf][1][r];
        float s2 = accS[qf][2][r], s3 = accS[qf][3][r];
        if (k0 +      l16 == qg) s0 = -1e30f;   // LSA diagonal mask
        if (k0 + 16 + l16 == qg) s1 = -1e30f;
        if (k0 + 32 + l16 == qg) s2 = -1e30f;
        if (k0 + 48 + l16 == qg) s3 = -1e30f;
        float tmax = fmaxf(fmaxf(s0, s1), fmaxf(s2, s3));
        #pragma unroll
        for (int off = 1; off < 16; off <<= 1) tmax = fmaxf(tmax, __shfl_xor(tmax, off));
        float mnew = fmaxf(mrow[qf][r], tmax);
        float alpha = __expf(mrow[qf][r] - mnew);
        float p0 = __expf(s0 - mnew), p1 = __expf(s1 - mnew);
        float p2 = __expf(s2 - mnew), p3 = __expf(s3 - mnew);
        float rs = (p0 + p1) + (p2 + p3);
        #pragma unroll
        for (int off = 1; off < 16; off <<= 1) rs += __shfl_xor(rs, off);
        lrow[qf][r] = lrow[qf][r] * alpha + rs;
        mrow[qf][r] = mnew;
        #pragma unroll
        for (int d = 0; d < 4; ++d) accO[qf][d][r] *= alpha;
        int prow = qf * 16 + lq * 4 + r;
        Pl[wid][prow][     l16] = f2bf(p0);
        Pl[wid][prow][16 + l16] = f2bf(p1);
        Pl[wid][prow][32 + l16] = f2bf(p2);
        Pl[wid][prow][48 + l16] = f2bf(p3);
      }
    }

    // ---- O += P V
    short8 vfr[4][2];
    #pragma unroll
    for (int d = 0; d < 4; ++d) {
      vfr[d][0] = *(const short8*)(vls + (d * 2 + 0) * 512 + lane * 8);
      vfr[d][1] = *(const short8*)(vls + (d * 2 + 1) * 512 + lane * 8);
    }
    #pragma unroll
    for (int qf = 0; qf < 2; ++qf) {
      short8 pa0 = *(const short8*)(&Pl[wid][qf * 16 + l16][lq * 8]);
      short8 pa1 = *(const short8*)(&Pl[wid][qf * 16 + l16][32 + lq * 8]);
      #pragma unroll
      for (int d = 0; d < 4; ++d) {
        accO[qf][d] = __builtin_amdgcn_mfma_f32_16x16x32_bf16(pa0, vfr[d][0], accO[qf][d], 0, 0, 0);
        accO[qf][d] = __builtin_amdgcn_mfma_f32_16x16x32_bf16(pa1, vfr[d][1], accO[qf][d], 0, 0, 0);
      }
    }

    __syncthreads();   // drains prefetch vmcnt + protects buffer reuse
  }

  #pragma unroll
  for (int qf = 0; qf < 2; ++qf)
    #pragma unroll
    for (int d = 0; d < 4; ++d)
      #pragma unroll
      for (int r = 0; r < 4; ++r) {
        int qg = q0 + qf * 16 + lq * 4 + r;
        float v = accO[qf][d][r] / lrow[qf][r];
        out[(size_t)(b * 2048 + qg) * 512 + h * 64 + d * 16 + l16] = f2bf(v);
      }
}

// ---------------- launcher ----------------
extern "C" void kernel_launch(void* const* d_in, const int* in_sizes, int n_in,
                              void* d_out, int out_size, void* d_ws, size_t ws_size,
                              hipStream_t stream)
{
  const float* x    = (const float*)d_in[0];
  const float* ln1g = (const float*)d_in[1];
  const float* ln1b = (const float*)d_in[2];
  const float* Wqkv = (const float*)d_in[3];
  const float* temp = (const float*)d_in[4];
  const float* Wo   = (const float*)d_in[5];
  const float* bo   = (const float*)d_in[6];
  const float* ln2g = (const float*)d_in[7];
  const float* ln2b = (const float*)d_in[8];
  const float* W1   = (const float*)d_in[9];
  const float* b1   = (const float*)d_in[10];
  const float* W2   = (const float*)d_in[11];
  const float* b2   = (const float*)d_in[12];
  float* out = (float*)d_out;

  char* ws = (char*)d_ws;
  short* wqkv_t = (short*)(ws);                    // [1536][512] bf16
  short* wo_t   = (short*)(ws + 1572864);          // [512][512]
  short* w1_t   = (short*)(ws + 2097152);          // [2048][512]
  short* w2_t   = (short*)(ws + 4194304);          // [512][2048]
  short* h      = (short*)(ws + 6291456);          // [8192][512] bf16 (LN out, reused)
  short* qkv    = (short*)(ws + 14680064);         // [8192][1536] bf16
  short* attn   = (short*)(ws + 39845888);         // [8192][512] bf16
  float* y      = (float*)(ws + 48234496);         // [8192][512] f32 (written AFTER attn)
  short* vt     = (short*)(ws + 48234496);         // [32][64][2048] bf16 (dead once y written)
  short* t      = (short*)(ws + 14680064);         // [8192][2048] bf16 (reuses qkv+attn)
  // ws high-water: 65,011,712 bytes (unchanged from passing round)

  const int M = 8192;

  transpose_bf16_kernel<<<dim3(1536 / 32, 512 / 32),  256, 0, stream>>>(Wqkv, wqkv_t, 512, 1536);
  transpose_bf16_kernel<<<dim3(512 / 32, 512 / 32),   256, 0, stream>>>(Wo,   wo_t,   512, 512);
  transpose_bf16_kernel<<<dim3(2048 / 32, 512 / 32),  256, 0, stream>>>(W1,   w1_t,   512, 2048);
  transpose_bf16_kernel<<<dim3(512 / 32, 2048 / 32),  256, 0, stream>>>(W2,   w2_t,   2048, 512);

  ln_kernel<<<M, 256, 0, stream>>>(x, ln1g, ln1b, h);

  gemm_bt_kernel<3, short><<<dim3(1536 / 128, M / 128), 256, 0, stream>>>(
      h, wqkv_t, qkv, nullptr, nullptr, vt, M, 1536, 512);

  attn_kernel<<<dim3(16, 32), 256, 0, stream>>>(qkv, vt, temp, attn);

  gemm_bt_kernel<1, float><<<dim3(512 / 128, M / 128), 256, 0, stream>>>(
      attn, wo_t, y, bo, x, nullptr, M, 512, 512);

  ln_kernel<<<M, 256, 0, stream>>>(y, ln2g, ln2b, h);

  gemm_bt_kernel<2, short><<<dim3(2048 / 128, M / 128), 256, 0, stream>>>(
      h, w1_t, t, b1, nullptr, nullptr, M, 2048, 512);

  gemm_bt_kernel<1, float><<<dim3(512 / 128, M / 128), 256, 0, stream>>>(
      t, w2_t, out, b2, y, nullptr, M, 512, 2048);

  hipMemcpyAsync(out + (size_t)M * 512, x, (size_t)M * 512 * sizeof(float),
                 hipMemcpyDeviceToDevice, stream);
}

// Round 3
// 240.968 us; speedup vs baseline: 1.4549x; 1.2237x over previous
//
#include <hip/hip_runtime.h>
#include <math.h>

typedef __attribute__((ext_vector_type(4))) float f32x4;
typedef __attribute__((ext_vector_type(8))) short short8;

#define DEV __device__ __forceinline__

DEV short f2bf(float f){
  union { float f; unsigned u; } v; v.f = f;
  unsigned r = v.u + 0x7fffu + ((v.u >> 16) & 1u);
  return (short)(r >> 16);
}
DEV float bf2f(short s){
  union { unsigned u; float f; } v; v.u = ((unsigned)(unsigned short)s) << 16; return v.f;
}
DEV float exp2_hw(float x){ float r; asm("v_exp_f32 %0, %1" : "=v"(r) : "v"(x)); return r; }
DEV float rcp_hw(float x){ float r; asm("v_rcp_f32 %0, %1" : "=v"(r) : "v"(x)); return r; }
DEV unsigned cvtpk(float a, float b){
  unsigned r; asm("v_cvt_pk_bf16_f32 %0, %1, %2" : "=v"(r) : "v"(a), "v"(b)); return r;
}

// ---------------- weight transpose + f32->bf16 ----------------
__global__ __launch_bounds__(256) void transpose_bf16_kernel(
    const float* __restrict__ W, short* __restrict__ Wt, int K, int N)
{
  __shared__ float tile[32][33];
  int nb = blockIdx.x * 32, kb = blockIdx.y * 32;
  int tx = threadIdx.x & 31, ty = threadIdx.x >> 5;   // ty 0..7
  #pragma unroll
  for (int i = ty; i < 32; i += 8)
    tile[i][tx] = W[(size_t)(kb + i) * N + nb + tx];
  __syncthreads();
  #pragma unroll
  for (int i = ty; i < 32; i += 8)
    Wt[(size_t)(nb + i) * K + kb + tx] = f2bf(tile[tx][i]);
}

// ---------------- layernorm (f32 in, bf16 out), one row / block ----------------
__global__ __launch_bounds__(256) void ln_kernel(
    const float* __restrict__ x, const float* __restrict__ g,
    const float* __restrict__ b, short* __restrict__ out)
{
  int row = blockIdx.x;
  int tid = threadIdx.x;
  const float* xr = x + (size_t)row * 512;
  float2 v = *(const float2*)(xr + tid * 2);
  float s = v.x + v.y;
  float sq = v.x * v.x + v.y * v.y;
  #pragma unroll
  for (int off = 1; off < 64; off <<= 1) {
    s  += __shfl_xor(s, off);
    sq += __shfl_xor(sq, off);
  }
  __shared__ float ss[4], sg[4];
  int wid = tid >> 6, lane = tid & 63;
  if (lane == 0) { ss[wid] = s; sg[wid] = sq; }
  __syncthreads();
  s  = ss[0] + ss[1] + ss[2] + ss[3];
  sq = sg[0] + sg[1] + sg[2] + sg[3];
  float mu  = s * (1.0f / 512.0f);
  float var = sq * (1.0f / 512.0f) - mu * mu;
  float rstd = rsqrtf(var + 1e-5f);
  float2 gg = *(const float2*)(g + tid * 2);
  float2 bb = *(const float2*)(b + tid * 2);
  float o0 = (v.x - mu) * rstd * gg.x + bb.x;
  float o1 = (v.y - mu) * rstd * gg.y + bb.y;
  unsigned pack = (unsigned)(unsigned short)f2bf(o0)
                | ((unsigned)(unsigned short)f2bf(o1) << 16);
  *(unsigned*)(out + (size_t)row * 512 + tid * 2) = pack;
}

// ---------------- GEMM: C[M,N] = A[M,K] * Bt[N,K]^T  (bf16 in, f32 acc) ----------------
// EPI: 0 = plain -> bf16 ; 1 = +bias +resid -> f32 ; 2 = +bias, GELU -> bf16
// EPI: 3 = plain -> bf16, plus key-swizzled transposed copy of cols>=1024 into vt
template<int EPI, typename OutT>
__global__ __launch_bounds__(256) void gemm_bt_kernel(
    const short* __restrict__ A, const short* __restrict__ Bt,
    OutT* __restrict__ C, const float* __restrict__ bias,
    const float* __restrict__ resid, short* __restrict__ vt,
    int M, int N, int K)
{
  __shared__ __align__(16) short As[128 * 32];
  __shared__ __align__(16) short Bs[128 * 32];
  int tid = threadIdx.x;
  int lane = tid & 63, wid = tid >> 6;
  int l16 = lane & 15, lq = lane >> 4;
  int bm = blockIdx.y, bn = blockIdx.x;
  int wm = wid >> 1, wn = wid & 1;

  f32x4 acc[4][4] = {};

  for (int k0 = 0; k0 < K; k0 += 32) {
    #pragma unroll
    for (int i = 0; i < 2; ++i) {
      int ci = i * 256 + tid;
      int row = ci >> 2, c4 = ci & 3;
      const short* ga = A  + (size_t)(bm * 128 + row) * K + k0 + c4 * 8;
      const short* gb = Bt + (size_t)(bn * 128 + row) * K + k0 + c4 * 8;
      __builtin_amdgcn_global_load_lds(
          (const __attribute__((address_space(1))) void*)ga,
          (__attribute__((address_space(3))) void*)((char*)As + (i * 4 + wid) * 1024),
          16, 0, 0);
      __builtin_amdgcn_global_load_lds(
          (const __attribute__((address_space(1))) void*)gb,
          (__attribute__((address_space(3))) void*)((char*)Bs + (i * 4 + wid) * 1024),
          16, 0, 0);
    }
    __syncthreads();
    short8 af[4], bfr[4];
    #pragma unroll
    for (int m = 0; m < 4; ++m)
      af[m] = *(const short8*)(As + (wm * 64 + m * 16 + l16) * 32 + lq * 8);
    #pragma unroll
    for (int n = 0; n < 4; ++n)
      bfr[n] = *(const short8*)(Bs + (wn * 64 + n * 16 + l16) * 32 + lq * 8);
    #pragma unroll
    for (int m = 0; m < 4; ++m)
      #pragma unroll
      for (int n = 0; n < 4; ++n)
        acc[m][n] = __builtin_amdgcn_mfma_f32_16x16x32_bf16(af[m], bfr[n], acc[m][n], 0, 0, 0);
    __syncthreads();
  }

  #pragma unroll
  for (int m = 0; m < 4; ++m) {
    #pragma unroll
    for (int n = 0; n < 4; ++n) {
      int col = bn * 128 + wn * 64 + n * 16 + l16;
      float bv = (EPI == 0 || EPI == 3) ? 0.0f : bias[col];
      #pragma unroll
      for (int r = 0; r < 4; ++r) {
        int row = bm * 128 + wm * 64 + m * 16 + lq * 4 + r;
        float v = acc[m][n][r];
        if (EPI == 1 || EPI == 2) v += bv;
        if (EPI == 2) v = 0.5f * v * (1.0f + erff(v * 0.70710678f));
        if (EPI == 1) v += resid[(size_t)row * N + col];
        if constexpr (sizeof(OutT) == 2) {
          short bw = f2bf(v);
          ((short*)C)[(size_t)row * N + col] = bw;
          if (EPI == 3 && col >= 1024) {   // V columns -> transposed [bh][d][n]
            int c2 = col - 1024;           // h*64 + d
            int bb2 = row >> 11, nn = row & 2047;
            int nns = (nn & 8) ? (nn ^ 4) : nn;   // key swizzle for attn PV operand order
            vt[(((size_t)(bb2 * 8 + (c2 >> 6))) * 64 + (c2 & 63)) * 2048 + nns] = bw;
          }
        } else {
          ((float*)C)[(size_t)row * N + col] = v;
        }
      }
    }
  }
}

// ---------------- fused flash attention with diagonal mask (LSA) ----------------
// Swapped-operand structure: S^T = mfma(K, Q) so each lane owns one q-column of P
// (16 key-values lane-local). In-register softmax (defer-max, exp2 domain),
// cvt_pk + 2-round shfl butterfly hands P^T to PV as mfma(V^T, P^T) = O^T.
// vt is key-swizzled (pos p<->p^4 for p&8) so no placement selects are needed.
__global__ __launch_bounds__(256, 2) void attn_kernel(
    const short* __restrict__ qkv, const short* __restrict__ vt,
    const float* __restrict__ temp_ptr, short* __restrict__ out)
{
  __shared__ __align__(16) short smem[16384];  // Ks[2][4096] | Vs[2][4096] shorts

  int tid = threadIdx.x;
  int lane = tid & 63, wid = tid >> 6;
  int l16 = lane & 15, lq = lane >> 4;
  int hi = lq >> 1, lq0 = lq & 1;
  int qb = blockIdx.x, bh = blockIdx.y;
  int b = bh >> 3, h = bh & 7;

  const short* qbase = qkv + (size_t)b * 2048 * 1536 + h * 64;
  const short* kbase = qbase + 512;
  const short* vbase = vt + (size_t)bh * 64 * 2048;

  float scale = __expf(temp_ptr[0]) * 1.44269504f;   // fold log2(e): exp2 domain
  int q0 = qb * 128 + wid * 32;

  // Q fragments, pre-scaled
  short8 qfrag[2][2];
  #pragma unroll
  for (int qf = 0; qf < 2; ++qf) {
    int qrow = q0 + qf * 16 + l16;
    #pragma unroll
    for (int c = 0; c < 2; ++c) {
      short8 raw = *(const short8*)(qbase + (size_t)qrow * 1536 + c * 32 + lq * 8);
      short8 sc;
      #pragma unroll
      for (int j = 0; j < 8; ++j) sc[j] = f2bf(bf2f(raw[j]) * scale);
      qfrag[qf][c] = sc;
    }
  }

  f32x4 accO[2][4] = {};
  float m[2] = {-10000.f, -10000.f};
  float l[2] = {0.f, 0.f};

  auto STAGE = [&](int bufi, int k0) {
    #pragma unroll
    for (int i = 0; i < 2; ++i) {
      int w16 = i * 256 + tid;            // 0..511
      int sub = w16 >> 7;                 // ksub (K) / dsub (V)
      int cc  = (w16 >> 6) & 1;
      int lq2 = (w16 >> 4) & 3;
      int l2  = w16 & 15;
      const short* srcK = kbase + (size_t)(k0 + sub * 16 + l2) * 1536 + cc * 32 + lq2 * 8;
      __builtin_amdgcn_global_load_lds(
          (const __attribute__((address_space(1))) void*)srcK,
          (__attribute__((address_space(3))) void*)((char*)smem + bufi * 8192 + (i * 4 + wid) * 1024),
          16, 0, 0);
      const short* srcV = vbase + (size_t)(sub * 16 + l2) * 2048 + k0 + cc * 32 + lq2 * 8;
      __builtin_amdgcn_global_load_lds(
          (const __attribute__((address_space(1))) void*)srcV,
          (__attribute__((address_space(3))) void*)((char*)smem + 16384 + bufi * 8192 + (i * 4 + wid) * 1024),
          16, 0, 0);
    }
  };

  STAGE(0, 0);
  asm volatile("s_waitcnt vmcnt(0)");
  __syncthreads();

  for (int k0 = 0; k0 < 2048; k0 += 64) {
    int cur = (k0 >> 6) & 1;
    if (k0 + 64 < 2048) STAGE(cur ^ 1, k0 + 64);

    const short* kls = smem + cur * 4096;
    const short* vls = smem + 8192 + cur * 4096;

    // ---- S^T = K Q^T : accS[qf][s] row=key s*16+lq*4+r, col=q=l16
    f32x4 accS[2][4] = {};
    #pragma unroll
    for (int s = 0; s < 4; ++s) {
      short8 kf0 = *(const short8*)(kls + (s * 2 + 0) * 512 + lane * 8);
      short8 kf1 = *(const short8*)(kls + (s * 2 + 1) * 512 + lane * 8);
      #pragma unroll
      for (int qf = 0; qf < 2; ++qf) {
        accS[qf][s] = __builtin_amdgcn_mfma_f32_16x16x32_bf16(kf0, qfrag[qf][0], accS[qf][s], 0, 0, 0);
        accS[qf][s] = __builtin_amdgcn_mfma_f32_16x16x32_bf16(kf1, qfrag[qf][1], accS[qf][s], 0, 0, 0);
      }
    }

    // ---- LSA diagonal mask: only one tile intersects this wave's q-range
    if ((q0 & ~63) == k0) {
      #pragma unroll
      for (int qf = 0; qf < 2; ++qf) {
        int qg = q0 + qf * 16 + l16;
        #pragma unroll
        for (int s = 0; s < 4; ++s)
          #pragma unroll
          for (int r = 0; r < 4; ++r)
            if (k0 + s * 16 + lq * 4 + r == qg) accS[qf][s][r] = -30000.f;
      }
    }

    // ---- tile max (lane-local tree + 2 shfls), defer-max decision
    float tmax[2];
    #pragma unroll
    for (int qf = 0; qf < 2; ++qf) {
      float t0 = fmaxf(fmaxf(accS[qf][0][0], accS[qf][0][1]), fmaxf(accS[qf][0][2], accS[qf][0][3]));
      float t1 = fmaxf(fmaxf(accS[qf][1][0], accS[qf][1][1]), fmaxf(accS[qf][1][2], accS[qf][1][3]));
      float t2 = fmaxf(fmaxf(accS[qf][2][0], accS[qf][2][1]), fmaxf(accS[qf][2][2], accS[qf][2][3]));
      float t3 = fmaxf(fmaxf(accS[qf][3][0], accS[qf][3][1]), fmaxf(accS[qf][3][2], accS[qf][3][3]));
      float tm = fmaxf(fmaxf(t0, t1), fmaxf(t2, t3));
      tm = fmaxf(tm, __shfl_xor(tm, 16));
      tm = fmaxf(tm, __shfl_xor(tm, 32));
      tmax[qf] = tm;
    }
    int need = !((tmax[0] <= m[0] + 11.5f) && (tmax[1] <= m[1] + 11.5f));
    if (__any(need)) {
      #pragma unroll
      for (int qf = 0; qf < 2; ++qf) {
        float mn = fmaxf(m[qf], tmax[qf]);
        float al = exp2_hw(m[qf] - mn);
        l[qf] *= al;
        #pragma unroll
        for (int d = 0; d < 4; ++d) accO[qf][d] *= al;
        m[qf] = mn;
      }
    }

    // ---- exp2 + sum + pack + 2-round butterfly transpose -> pa[qf][c]
    short8 pa[2][2];
    #pragma unroll
    for (int qf = 0; qf < 2; ++qf) {
      float sum = 0.f;
      unsigned W[4][2];
      #pragma unroll
      for (int s = 0; s < 4; ++s) {
        float p0 = exp2_hw(accS[qf][s][0] - m[qf]);
        float p1 = exp2_hw(accS[qf][s][1] - m[qf]);
        float p2 = exp2_hw(accS[qf][s][2] - m[qf]);
        float p3 = exp2_hw(accS[qf][s][3] - m[qf]);
        sum += (p0 + p1) + (p2 + p3);
        W[s][0] = cvtpk(p0, p1);
        W[s][1] = cvtpk(p2, p3);
      }
      sum += __shfl_xor(sum, 16);
      sum += __shfl_xor(sum, 32);
      l[qf] += sum;

      unsigned K0[2], S0[2], K2[2], S2[2], R0[2], R2[2];
      #pragma unroll
      for (int w = 0; w < 2; ++w) {
        K0[w] = hi ? W[1][w] : W[0][w];
        S0[w] = hi ? W[0][w] : W[1][w];
        K2[w] = hi ? W[3][w] : W[2][w];
        S2[w] = hi ? W[2][w] : W[3][w];
      }
      #pragma unroll
      for (int w = 0; w < 2; ++w) {
        R0[w] = (unsigned)__shfl_xor((int)S0[w], 32);
        R2[w] = (unsigned)__shfl_xor((int)S2[w], 32);
      }
      bool sw = (hi != lq0);
      unsigned FA[2], FB[2], sA[2], sB[2], GA[2], GB[2];
      #pragma unroll
      for (int w = 0; w < 2; ++w) {
        sA[w] = sw ? K0[w] : R0[w];  FA[w] = sw ? R0[w] : K0[w];
        sB[w] = sw ? K2[w] : R2[w];  FB[w] = sw ? R2[w] : K2[w];
      }
      #pragma unroll
      for (int w = 0; w < 2; ++w) {
        GA[w] = (unsigned)__shfl_xor((int)sA[w], 16);
        GB[w] = (unsigned)__shfl_xor((int)sB[w], 16);
      }
      union { unsigned u[4]; short8 s8; } p0u, p1u;
      p0u.u[0] = FA[0]; p0u.u[1] = FA[1]; p0u.u[2] = GA[0]; p0u.u[3] = GA[1];
      p1u.u[0] = FB[0]; p1u.u[1] = FB[1]; p1u.u[2] = GB[0]; p1u.u[3] = GB[1];
      pa[qf][0] = p0u.s8;
      pa[qf][1] = p1u.s8;
    }

    // ---- O^T += V^T P^T
    short8 vfr[4][2];
    #pragma unroll
    for (int d = 0; d < 4; ++d) {
      vfr[d][0] = *(const short8*)(vls + (d * 2 + 0) * 512 + lane * 8);
      vfr[d][1] = *(const short8*)(vls + (d * 2 + 1) * 512 + lane * 8);
    }
    #pragma unroll
    for (int qf = 0; qf < 2; ++qf)
      #pragma unroll
      for (int d = 0; d < 4; ++d) {
        accO[qf][d] = __builtin_amdgcn_mfma_f32_16x16x32_bf16(vfr[d][0], pa[qf][0], accO[qf][d], 0, 0, 0);
        accO[qf][d] = __builtin_amdgcn_mfma_f32_16x16x32_bf16(vfr[d][1], pa[qf][1], accO[qf][d], 0, 0, 0);
      }

    __syncthreads();
  }

  // ---- epilogue: out[q][h*64+d] = accO^T / l  (8B packed stores)
  #pragma unroll
  for (int qf = 0; qf < 2; ++qf) {
    float inv = rcp_hw(l[qf]);
    int qg = q0 + qf * 16 + l16;
    size_t rowoff = (size_t)(b * 2048 + qg) * 512 + h * 64;
    #pragma unroll
    for (int d = 0; d < 4; ++d) {
      unsigned w0 = cvtpk(accO[qf][d][0] * inv, accO[qf][d][1] * inv);
      unsigned w1 = cvtpk(accO[qf][d][2] * inv, accO[qf][d][3] * inv);
      uint2 pk; pk.x = w0; pk.y = w1;
      *(uint2*)(out + rowoff + d * 16 + lq * 4) = pk;
    }
  }
}

// ---------------- launcher ----------------
extern "C" void kernel_launch(void* const* d_in, const int* in_sizes, int n_in,
                              void* d_out, int out_size, void* d_ws, size_t ws_size,
                              hipStream_t stream)
{
  const float* x    = (const float*)d_in[0];
  const float* ln1g = (const float*)d_in[1];
  const float* ln1b = (const float*)d_in[2];
  const float* Wqkv = (const float*)d_in[3];
  const float* temp = (const float*)d_in[4];
  const float* Wo   = (const float*)d_in[5];
  const float* bo   = (const float*)d_in[6];
  const float* ln2g = (const float*)d_in[7];
  const float* ln2b = (const float*)d_in[8];
  const float* W1   = (const float*)d_in[9];
  const float* b1   = (const float*)d_in[10];
  const float* W2   = (const float*)d_in[11];
  const float* b2   = (const float*)d_in[12];
  float* out = (float*)d_out;

  char* ws = (char*)d_ws;
  short* wqkv_t = (short*)(ws);                    // [1536][512] bf16
  short* wo_t   = (short*)(ws + 1572864);          // [512][512]
  short* w1_t   = (short*)(ws + 2097152);          // [2048][512]
  short* w2_t   = (short*)(ws + 4194304);          // [512][2048]
  short* h      = (short*)(ws + 6291456);          // [8192][512] bf16 (LN out, reused)
  short* qkv    = (short*)(ws + 14680064);         // [8192][1536] bf16
  short* attn   = (short*)(ws + 39845888);         // [8192][512] bf16
  float* y      = (float*)(ws + 48234496);         // [8192][512] f32 (written AFTER attn)
  short* vt     = (short*)(ws + 48234496);         // [32][64][2048] bf16 (dead once y written)
  short* t      = (short*)(ws + 14680064);         // [8192][2048] bf16 (reuses qkv+attn)
  // ws high-water: 65,011,712 bytes

  const int M = 8192;

  transpose_bf16_kernel<<<dim3(1536 / 32, 512 / 32),  256, 0, stream>>>(Wqkv, wqkv_t, 512, 1536);
  transpose_bf16_kernel<<<dim3(512 / 32, 512 / 32),   256, 0, stream>>>(Wo,   wo_t,   512, 512);
  transpose_bf16_kernel<<<dim3(2048 / 32, 512 / 32),  256, 0, stream>>>(W1,   w1_t,   512, 2048);
  transpose_bf16_kernel<<<dim3(512 / 32, 2048 / 32),  256, 0, stream>>>(W2,   w2_t,   2048, 512);

  ln_kernel<<<M, 256, 0, stream>>>(x, ln1g, ln1b, h);

  gemm_bt_kernel<3, short><<<dim3(1536 / 128, M / 128), 256, 0, stream>>>(
      h, wqkv_t, qkv, nullptr, nullptr, vt, M, 1536, 512);

  attn_kernel<<<dim3(16, 32), 256, 0, stream>>>(qkv, vt, temp, attn);

  gemm_bt_kernel<1, float><<<dim3(512 / 128, M / 128), 256, 0, stream>>>(
      attn, wo_t, y, bo, x, nullptr, M, 512, 512);

  ln_kernel<<<M, 256, 0, stream>>>(y, ln2g, ln2b, h);

  gemm_bt_kernel<2, short><<<dim3(2048 / 128, M / 128), 256, 0, stream>>>(
      h, w1_t, t, b1, nullptr, nullptr, M, 2048, 512);

  gemm_bt_kernel<1, float><<<dim3(512 / 128, M / 128), 256, 0, stream>>>(
      t, w2_t, out, b2, y, nullptr, M, 512, 2048);

  hipMemcpyAsync(out + (size_t)M * 512, x, (size_t)M * 512 * sizeof(float),
                 hipMemcpyDeviceToDevice, stream);
}